// Round 6
// baseline (205.883 us; speedup 1.0000x reference)
//
#include <hip/hip_runtime.h>
#include <hip/hip_fp16.h>
#include <stdint.h>

#define NCH 128            // C_IN == C_OUT == 128
#define BK_SHIFT 9         // 512 targets per bucket
#define BK_TGTS 512
#define NBUCK_MAX 128
#define PT_EDGES 8192      // edges per partition tile
#define BS_CAP 18432       // bucket_sort LDS capacity (mean 16384, +16 sigma)

typedef short bf16x8 __attribute__((ext_vector_type(8)));
typedef float f32x4 __attribute__((ext_vector_type(4)));

// ---------------------------------------------------------------------------
// bf16 helpers (manual RNE pack; decode via bit shift)
// ---------------------------------------------------------------------------
__device__ __forceinline__ unsigned short f2bf(float f) {
    union { float f; uint32_t u; } v; v.f = f;
    uint32_t u = v.u;
    uint32_t r = u + 0x7fffu + ((u >> 16) & 1u);
    return (unsigned short)(r >> 16);
}
__device__ __forceinline__ float bf2f(unsigned short h) {
    return __uint_as_float((uint32_t)h << 16);
}
__device__ __forceinline__ float bflo(uint32_t u) { return __uint_as_float(u << 16); }
__device__ __forceinline__ float bfhi(uint32_t u) { return __uint_as_float(u & 0xffff0000u); }

// ---------------------------------------------------------------------------
// Detect whether edge_index buffer is int64 (odd int32 words all zero) or int32.
// ---------------------------------------------------------------------------
__global__ void detect_idx64_kernel(const int* __restrict__ ei, int* __restrict__ flag) {
    if (blockIdx.x == 0 && threadIdx.x == 0) {
        int nz = 0;
        for (int i = 0; i < 128; ++i) nz |= ei[2 * i + 1];
        *flag = (nz == 0) ? 1 : 0;
    }
}

__device__ __forceinline__ int load_row(const int* ei, int E, int e, bool is64) {
    return is64 ? ei[2 * (size_t)e] : ei[e];
}
__device__ __forceinline__ int load_col(const int* ei, int E, int e, bool is64) {
    return is64 ? ei[2 * (size_t)E + 2 * (size_t)e] : ei[(size_t)E + e];
}

// ---------------------------------------------------------------------------
// Stage 1: per-bucket edge counts (LDS-aggregated histogram of c >> BK_SHIFT).
// ---------------------------------------------------------------------------
__global__ __launch_bounds__(256) void bucket_count_kernel(const int* __restrict__ ei, int E,
                                                           const int* __restrict__ flag,
                                                           int* __restrict__ bcnt) {
    __shared__ int hist[NBUCK_MAX];
    const bool is64 = (*flag != 0);
    const int t = threadIdx.x;
    for (int i = t; i < NBUCK_MAX; i += 256) hist[i] = 0;
    __syncthreads();
    int i = blockIdx.x * 256 + t;
    const int stride = gridDim.x * 256;
    for (; i < E; i += stride) {
        int c = load_col(ei, E, i, is64);
        atomicAdd(&hist[c >> BK_SHIFT], 1);
    }
    __syncthreads();
    for (int b = t; b < NBUCK_MAX; b += 256) {
        if (hist[b]) atomicAdd(&bcnt[b], hist[b]);
    }
}

// ---------------------------------------------------------------------------
// Stage 2: one-wave exclusive scan of bucket counts -> bbase, init bcur.
// ---------------------------------------------------------------------------
__global__ void bucket_scan_kernel(const int* __restrict__ bcnt, int nbuck,
                                   int* __restrict__ bbase, int* __restrict__ bcur) {
    const int t = threadIdx.x;  // 64
    int carry = 0;
    for (int base = 0; base < nbuck; base += 64) {
        const int i = base + t;
        const int orig = (i < nbuck) ? bcnt[i] : 0;
        int v = orig;
        for (int d = 1; d < 64; d <<= 1) {
            int u = __shfl_up(v, d);
            if (t >= d) v += u;
        }
        if (i < nbuck) { bbase[i] = carry + v - orig; bcur[i] = carry + v - orig; }
        carry += __shfl(v, 63);
    }
    if (t == 0) bbase[nbuck] = carry;  // == E
}

// ---------------------------------------------------------------------------
// Stage 3: partition edges into buckets. Packed entry = {c:16 | r:16}.
// ---------------------------------------------------------------------------
__global__ __launch_bounds__(256) void partition_kernel(const int* __restrict__ ei, int E,
                                                        const int* __restrict__ flag, int nbuck,
                                                        int* __restrict__ bcur,
                                                        uint32_t* __restrict__ bkt) {
    __shared__ int hist[NBUCK_MAX];
    __shared__ int cbase[NBUCK_MAX];
    __shared__ uint32_t stage[PT_EDGES];
    const bool is64 = (*flag != 0);
    const int t = threadIdx.x;
    const int e0 = blockIdx.x * PT_EDGES;
    const int cnt = min(PT_EDGES, E - e0);

    for (int i = t; i < NBUCK_MAX; i += 256) hist[i] = 0;
    __syncthreads();

    int rank[PT_EDGES / 256];
    #pragma unroll
    for (int j = 0; j < PT_EDGES / 256; ++j) {
        const int i = t + j * 256;
        if (i < cnt) {
            const int r = load_row(ei, E, e0 + i, is64);
            const int c = load_col(ei, E, e0 + i, is64);
            stage[i] = ((uint32_t)c << 16) | (uint32_t)r;
            rank[j] = atomicAdd(&hist[c >> BK_SHIFT], 1);
        }
    }
    __syncthreads();
    for (int b = t; b < nbuck; b += 256) {
        cbase[b] = hist[b] ? atomicAdd(&bcur[b], hist[b]) : 0;
    }
    __syncthreads();
    #pragma unroll
    for (int j = 0; j < PT_EDGES / 256; ++j) {
        const int i = t + j * 256;
        if (i < cnt) {
            const uint32_t p = stage[i];
            const int b = (int)(p >> (16 + BK_SHIFT));
            bkt[cbase[b] + rank[j]] = p;
        }
    }
}

// ---------------------------------------------------------------------------
// Stage 4: one block per bucket. Counting sort in LDS.
// ---------------------------------------------------------------------------
__global__ __launch_bounds__(256) void bucket_sort_kernel(const uint32_t* __restrict__ bkt,
                                                          const int* __restrict__ bbase,
                                                          int N, int nbuck,
                                                          unsigned short* __restrict__ entries,
                                                          int* __restrict__ offsets,
                                                          float* __restrict__ dinv) {
    __shared__ uint32_t se[BS_CAP];
    __shared__ int hist[BK_TGTS];
    __shared__ int lofs[BK_TGTS];
    __shared__ int sm[256];
    const int b = blockIdx.x;
    const int t = threadIdx.x;
    const int c0 = b << BK_SHIFT;
    const int ntgt = min(BK_TGTS, N - c0);
    const int beg = bbase[b];
    const int nE = bbase[b + 1] - beg;

    for (int i = t; i < BK_TGTS; i += 256) hist[i] = 0;
    __syncthreads();
    for (int i = t; i < nE; i += 256) {
        const uint32_t p = bkt[beg + i];
        se[i] = p;
        atomicAdd(&hist[(int)(p >> 16) - c0], 1);
    }
    __syncthreads();

    const int h0 = hist[2 * t], h1 = hist[2 * t + 1];
    sm[t] = h0 + h1;
    __syncthreads();
    for (int d = 1; d < 256; d <<= 1) {
        int u = (t >= d) ? sm[t - d] : 0;
        __syncthreads();
        sm[t] += u;
        __syncthreads();
    }
    const int ex = sm[t] - (h0 + h1);
    lofs[2 * t] = ex;
    lofs[2 * t + 1] = ex + h0;
    __syncthreads();

    for (int i = t; i < ntgt; i += 256) {
        offsets[c0 + i] = beg + lofs[i];
        dinv[c0 + i] = rsqrtf((float)(hist[i] + 1));
    }
    if (t == 0 && b == nbuck - 1) offsets[N] = bbase[nbuck];
    __syncthreads();

    for (int i = t; i < BK_TGTS; i += 256) hist[i] = lofs[i];
    __syncthreads();
    for (int i = t; i < nE; i += 256) {
        const uint32_t p = se[i];
        const int tgt = (int)(p >> 16) - c0;
        const int pos = atomicAdd(&hist[tgt], 1);
        entries[beg + pos] = (unsigned short)(p & 0xffffu);
    }
}

// ---------------------------------------------------------------------------
// h = x @ W via MFMA bf16, 3-term split; output pre-scaled by dinv[row]:
//   hb[row] = bf16( dinv[row] * (x @ W)[row] )
// ---------------------------------------------------------------------------
__global__ __launch_bounds__(256) void gemm_xw_mfma_kernel(const float* __restrict__ x,
                                                           const float* __restrict__ W,
                                                           const float* __restrict__ dinv,
                                                           uint32_t* __restrict__ hb, int N) {
    __shared__ short sW[2][4][8][64][8];
    const int t = threadIdx.x;

    {
        const int n = t & 127;
        const int hseg = t >> 7;
        const int ct = n >> 4;
        const int l16 = n & 15;
        for (int ko = hseg * 8; ko < hseg * 8 + 8; ++ko) {
            const int kt = ko >> 2;
            const int g = ko & 3;
            bf16x8 vh, vl;
            #pragma unroll
            for (int e = 0; e < 8; ++e) {
                const float w = W[(size_t)(ko * 8 + e) * NCH + n];
                const unsigned short wh = f2bf(w);
                const float rem = w - bf2f(wh);
                vh[e] = (short)wh;
                vl[e] = (short)f2bf(rem);
            }
            *reinterpret_cast<bf16x8*>(&sW[0][kt][ct][g * 16 + l16][0]) = vh;
            *reinterpret_cast<bf16x8*>(&sW[1][kt][ct][g * 16 + l16][0]) = vl;
        }
    }
    __syncthreads();

    const int wave = t >> 6;
    const int lane = t & 63;
    const int g = lane >> 4;
    const int l16 = lane & 15;
    const int row0 = blockIdx.x * 64 + wave * 16;
    if (row0 >= N) return;
    const int arow = min(row0 + l16, N - 1);

    bf16x8 ah[4], al[4];
    const float* xr = x + (size_t)arow * NCH + g * 8;
    #pragma unroll
    for (int kt = 0; kt < 4; ++kt) {
        const float4 v0 = *reinterpret_cast<const float4*>(xr + kt * 32);
        const float4 v1 = *reinterpret_cast<const float4*>(xr + kt * 32 + 4);
        const float vv[8] = {v0.x, v0.y, v0.z, v0.w, v1.x, v1.y, v1.z, v1.w};
        #pragma unroll
        for (int e = 0; e < 8; ++e) {
            const unsigned short h16 = f2bf(vv[e]);
            const float rem = vv[e] - bf2f(h16);
            ah[kt][e] = (short)h16;
            al[kt][e] = (short)f2bf(rem);
        }
    }

    float dn[4];
    #pragma unroll
    for (int r = 0; r < 4; ++r) dn[r] = dinv[min(row0 + g * 4 + r, N - 1)];

    #pragma unroll
    for (int ct = 0; ct < 8; ++ct) {
        f32x4 acc = {0.f, 0.f, 0.f, 0.f};
        #pragma unroll
        for (int kt = 0; kt < 4; ++kt) {
            const bf16x8 bh = *reinterpret_cast<const bf16x8*>(&sW[0][kt][ct][lane][0]);
            const bf16x8 bl = *reinterpret_cast<const bf16x8*>(&sW[1][kt][ct][lane][0]);
            acc = __builtin_amdgcn_mfma_f32_16x16x32_bf16(ah[kt], bh, acc, 0, 0, 0);
            acc = __builtin_amdgcn_mfma_f32_16x16x32_bf16(al[kt], bh, acc, 0, 0, 0);
            acc = __builtin_amdgcn_mfma_f32_16x16x32_bf16(ah[kt], bl, acc, 0, 0, 0);
        }
        #pragma unroll
        for (int r = 0; r < 4; ++r) {
            const float v = acc[r] * dn[r];
            const float o = __shfl_xor(v, 1);
            const int wrow = row0 + g * 4 + r;
            if ((lane & 1) == 0 && wrow < N) {
                const uint32_t p = (uint32_t)f2bf(v) | ((uint32_t)f2bf(o) << 16);
                hb[(size_t)wrow * (NCH / 2) + ct * 8 + (l16 >> 1)] = p;
            }
        }
    }
}

// ---------------------------------------------------------------------------
// SpMM, channel-sliced + XCD-affine:
//   slice = blockIdx & 3 (round-robin XCD dispatch -> each XCD sees ONE slice,
//   per-XCD gather working set 3.2 MB -> L2-resident).
// One node per wave; 8 edge-groups x 8 lanes; lane covers 4 cols (8 B = one
// aligned 64 B line per group gather). 2-deep unroll -> 16 edges in flight.
// ---------------------------------------------------------------------------
__global__ __launch_bounds__(256) void spmm_csr_kernel(const uint32_t* __restrict__ hb,
                                                       const unsigned short* __restrict__ entries,
                                                       const int* __restrict__ offsets,
                                                       const float* __restrict__ dinv,
                                                       const float* __restrict__ bias,
                                                       float* __restrict__ out, int N) {
    const int slice = blockIdx.x & 3;            // 32 cols per slice
    const int n = (blockIdx.x >> 2) * 4 + (threadIdx.x >> 6);
    if (n >= N) return;
    const int lane = threadIdx.x & 63;
    const int e = lane >> 3;                     // edge group 0..7
    const int c = lane & 7;                      // col quad within slice

    const int beg = offsets[n];
    const int end = offsets[n + 1];

    const uint32_t* hbs = hb + slice * 16 + c * 2;   // + src*64 (row stride 64 u32)

    float a0 = 0.f, a1 = 0.f, a2 = 0.f, a3 = 0.f;
    int i = beg + e;
    for (; i + 8 < end; i += 16) {
        const int s0 = entries[i];
        const int s1 = entries[i + 8];
        const uint2 u0 = *reinterpret_cast<const uint2*>(hbs + (size_t)s0 * (NCH / 2));
        const uint2 u1 = *reinterpret_cast<const uint2*>(hbs + (size_t)s1 * (NCH / 2));
        a0 += bflo(u0.x); a1 += bfhi(u0.x); a2 += bflo(u0.y); a3 += bfhi(u0.y);
        a0 += bflo(u1.x); a1 += bfhi(u1.x); a2 += bflo(u1.y); a3 += bfhi(u1.y);
    }
    if (i < end) {
        const int s0 = entries[i];
        const uint2 u0 = *reinterpret_cast<const uint2*>(hbs + (size_t)s0 * (NCH / 2));
        a0 += bflo(u0.x); a1 += bfhi(u0.x); a2 += bflo(u0.y); a3 += bfhi(u0.y);
    }

    // reduce over the 8 edge-groups (lanes differing in bits 3..5)
    a0 += __shfl_xor(a0, 8);  a1 += __shfl_xor(a1, 8);  a2 += __shfl_xor(a2, 8);  a3 += __shfl_xor(a3, 8);
    a0 += __shfl_xor(a0, 16); a1 += __shfl_xor(a1, 16); a2 += __shfl_xor(a2, 16); a3 += __shfl_xor(a3, 16);
    a0 += __shfl_xor(a0, 32); a1 += __shfl_xor(a1, 32); a2 += __shfl_xor(a2, 32); a3 += __shfl_xor(a3, 32);

    if (e == 0) {
        // self-loop: hb[n] is dinv[n]*h[n]
        const uint2 us = *reinterpret_cast<const uint2*>(hbs + (size_t)n * (NCH / 2));
        a0 += bflo(us.x); a1 += bfhi(us.x); a2 += bflo(us.y); a3 += bfhi(us.y);
        const float s = dinv[n];
        const float4 bb = reinterpret_cast<const float4*>(bias + slice * 32)[c];
        float4 o;
        o.x = fmaxf(a0 * s + bb.x, 0.f);
        o.y = fmaxf(a1 * s + bb.y, 0.f);
        o.z = fmaxf(a2 * s + bb.z, 0.f);
        o.w = fmaxf(a3 * s + bb.w, 0.f);
        reinterpret_cast<float4*>(out + (size_t)n * NCH + slice * 32)[c] = o;
    }
}

// ---------------------------------------------------------------------------
extern "C" void kernel_launch(void* const* d_in, const int* in_sizes, int n_in,
                              void* d_out, int out_size, void* d_ws, size_t ws_size,
                              hipStream_t stream) {
    const float* x = (const float*)d_in[0];
    const int* ei = (const int*)d_in[1];  // int32 view; int64 handled via flag
    const float* W = (const float*)d_in[2];
    const float* bias = (const float*)d_in[3];
    float* out = (float*)d_out;

    const int N = in_sizes[0] / NCH;       // 50000
    const int E = in_sizes[1] / 2;         // 1600000
    const int nbuck = (N + BK_TGTS - 1) >> BK_SHIFT;   // 98

    char* w = (char*)d_ws;
    const int padN = (N + 127) & ~127;
    const int padN1 = (N + 1 + 127) & ~127;
    int* offsets = (int*)w;                 w += (size_t)padN1 * 4;
    float* dinv = (float*)w;                w += (size_t)padN * 4;
    int* bcnt = (int*)w;                    w += NBUCK_MAX * 4;
    int* bbase = (int*)w;                   w += (NBUCK_MAX + 128) * 4;
    int* bcur = (int*)w;                    w += NBUCK_MAX * 4;
    int* flag = (int*)w;                    w += 512;
    // regionA: bkt (E*4 = 6.4 MB) while building; hb (N*64*4 = 12.8 MB) after
    uint32_t* bkt = (uint32_t*)w;
    uint32_t* hb = (uint32_t*)w;            w += (size_t)N * (NCH / 2) * 4;
    unsigned short* entries = (unsigned short*)w;  w += (size_t)E * 2;
    (void)ws_size;

    hipMemsetAsync(bcnt, 0, NBUCK_MAX * 4, stream);
    detect_idx64_kernel<<<1, 64, 0, stream>>>(ei, flag);

    bucket_count_kernel<<<1024, 256, 0, stream>>>(ei, E, flag, bcnt);
    bucket_scan_kernel<<<1, 64, 0, stream>>>(bcnt, nbuck, bbase, bcur);
    partition_kernel<<<(E + PT_EDGES - 1) / PT_EDGES, 256, 0, stream>>>(ei, E, flag, nbuck, bcur, bkt);
    bucket_sort_kernel<<<nbuck, 256, 0, stream>>>(bkt, bbase, N, nbuck, entries, offsets, dinv);

    gemm_xw_mfma_kernel<<<(N + 63) / 64, 256, 0, stream>>>(x, W, dinv, hb, N);

    spmm_csr_kernel<<<((N + 3) / 4) * 4, 256, 0, stream>>>(hb, entries, offsets, dinv, bias, out, N);
}